// Round 5
// baseline (622.712 us; speedup 1.0000x reference)
//
#include <hip/hip_runtime.h>
#include <math.h>

typedef unsigned short u16;
typedef unsigned int u32;
typedef __attribute__((ext_vector_type(2))) u32 u32x2;
typedef __attribute__((ext_vector_type(8))) short short8;
typedef __attribute__((ext_vector_type(4))) float f32x4;
typedef __attribute__((ext_vector_type(2))) float f32x2;

// ---------------- workspace layout (bytes) ----------------
// planes_t: 3*512*512 texels * 40 bf16 ch (c>=36 zero)   = 62,914,560
// lines_t : 3*512 texels * 40 bf16                        =    122,880
// w1s     : 16 nt * 5 kt * 64 lanes * 8 bf16              =     81,920
// w2s     : 12 nt * 8 kt * 64 lanes * 8 bf16              =     98,304
#define OFF_LINES_T 62914560u
#define OFF_W1S     63037440u
#define OFF_W2S     63119360u
#define WS_NEEDED   63217664u

__device__ __forceinline__ float bf_lo(u32 u){ union{u32 i;float f;} v; v.i = u << 16; return v.f; }
__device__ __forceinline__ float bf_hi(u32 u){ union{u32 i;float f;} v; v.i = u & 0xffff0000u; return v.f; }
// RTNE pack (precompute kernels only — cost irrelevant there)
__device__ __forceinline__ u16 f2bf(float f){ union{float f;u32 i;} v; v.f=f; u32 i=v.i; return (u16)((i + 0x7fffu + ((i>>16)&1u)) >> 16); }
__device__ __forceinline__ u32 pack2bf(float lo, float hi){ return (u32)f2bf(lo) | ((u32)f2bf(hi)<<16); }
// fast round-half-up pack: 2 adds + v_perm (vs ~9 inst RTNE); error <= 0.5 ulp
__device__ __forceinline__ u32 pack2bf_fast(float lo, float hi){
  return __builtin_amdgcn_perm(__float_as_uint(hi) + 0x8000u,
                               __float_as_uint(lo) + 0x8000u, 0x07060302u);
}
__device__ __forceinline__ u16 f2bf_fast(float f){ return (u16)((__float_as_uint(f) + 0x8000u) >> 16); }

// LDS k'-layout (160 slots): [0..35]=mode0, [36..39]=0, [40..75]=mode1, [76..79]=0,
// [80..115]=mode2, [116..119]=0, [120..140]=PE(21), [141..159]=0.
__device__ __forceinline__ int map_k1(int kp){
  if (kp < 120){ int g = kp/40, r = kp - g*40; return (r<36) ? g*36 + r : -1; }
  if (kp < 141) return kp - 12;   // 108 + (kp-120)
  return -1;
}

// ---------------- fused precompute: all transposes in ONE launch ----------------
// r4 evidence: store-coalesced rewrite changed total by ~nothing (residual
// 295->309us across two radically different k_pre structures, and k_pre never
// appears in top-5 dispatches) -> k_pre is small; residual is harness-fixed.
// Keeping the chunk-per-thread version (coalesced stores, near-coalesced reads).
#define NB_TP 15360
#define NB_TL 30
#define NB_W1 20
#define NB_W2 24
__global__ void k_pre(const float* __restrict__ planes, const float* __restrict__ lines,
                      const float* __restrict__ W1, const float* __restrict__ W2,
                      u16* __restrict__ pt, u16* __restrict__ lt,
                      u16* __restrict__ w1s, u16* __restrict__ w2s){
  const int b = blockIdx.x;
  const int tid = threadIdx.x;
  if (b < NB_TP){
    int m = b*256 + tid;                // chunk id 0..3,932,159
    int tt = m/5, cc = m - tt*5;        // texel 0..786431, chunk-in-texel 0..4
    int i = tt >> 18;
    int yx = tt & 262143;
    const float* src = planes + (size_t)i*9437184 + yx;   // i*36*262144 + y*512 + x
    int cbase = cc*8;
    float v[8];
#pragma unroll
    for (int e=0;e<8;e++) v[e] = 0.f;
    if (cc < 4){
#pragma unroll
      for (int e=0;e<8;e++) v[e] = src[(size_t)(cbase+e)*262144];
    } else {
#pragma unroll
      for (int e=0;e<4;e++) v[e] = src[(size_t)(32+e)*262144];
    }
    uint4 o; o.x=pack2bf(v[0],v[1]); o.y=pack2bf(v[2],v[3]); o.z=pack2bf(v[4],v[5]); o.w=pack2bf(v[6],v[7]);
    *reinterpret_cast<uint4*>(pt + (size_t)m*8) = o;      // byte m*16: lane-consecutive
  } else if (b < NB_TP+NB_TL){
    int m = (b-NB_TP)*256 + tid;        // chunk id 0..7679
    int tt = m/5, cc = m - tt*5;        // texel 0..1535
    int i = tt >> 9, g = tt & 511;
    const float* src = lines + (size_t)i*18432 + g;       // i*36*512 + g
    int cbase = cc*8;
    float v[8];
#pragma unroll
    for (int e=0;e<8;e++) v[e] = 0.f;
    if (cc < 4){
#pragma unroll
      for (int e=0;e<8;e++) v[e] = src[(size_t)(cbase+e)*512];
    } else {
#pragma unroll
      for (int e=0;e<4;e++) v[e] = src[(size_t)(32+e)*512];
    }
    uint4 o; o.x=pack2bf(v[0],v[1]); o.y=pack2bf(v[2],v[3]); o.z=pack2bf(v[4],v[5]); o.w=pack2bf(v[6],v[7]);
    *reinterpret_cast<uint4*>(lt + (size_t)m*8) = o;
  } else if (b < NB_TP+NB_TL+NB_W1){
    int t = (b-(NB_TP+NB_TL))*256 + tid;         // 0..5119 = 80 frags * 64 lanes
    int lane = t & 63;
    int fid = t >> 6;                            // nt*5 + kt
    int nt = fid/5, kt = fid - nt*5;
    int n = nt*16 + (lane & 15);
    int kb = kt*32 + (lane >> 4)*8;
    float v[8];
#pragma unroll
    for (int j=0;j<8;j++){ int k = map_k1(kb+j); v[j] = (k>=0) ? W1[k*256+n] : 0.f; }
    uint4 o; o.x=pack2bf(v[0],v[1]); o.y=pack2bf(v[2],v[3]); o.z=pack2bf(v[4],v[5]); o.w=pack2bf(v[6],v[7]);
    *reinterpret_cast<uint4*>(w1s + (size_t)t*8) = o;
  } else {
    int t = (b-(NB_TP+NB_TL+NB_W1))*256 + tid;   // 0..6143 = 96 frags * 64 lanes
    int lane = t & 63;
    int fid = t >> 6;                            // nt*8 + kt
    int kb = (fid & 7)*32 + (lane >> 4)*8;
    int n = (fid >> 3)*16 + (lane & 15);
    float v[8];
#pragma unroll
    for (int j=0;j<8;j++){ int k = kb+j; v[j] = (n<129) ? W2[k*129+n] : 0.f; }
    uint4 o; o.x=pack2bf(v[0],v[1]); o.y=pack2bf(v[2],v[3]); o.z=pack2bf(v[4],v[5]); o.w=pack2bf(v[6],v[7]);
    *reinterpret_cast<uint4*>(w2s + (size_t)t*8) = o;
  }
}

// unpack 2 packed bf16 -> float2 (2 VALU)
__device__ __forceinline__ f32x2 bfx2(u32 u){
  f32x2 r;
  r.x = __uint_as_float(u << 16);
  r.y = __uint_as_float(u & 0xffff0000u);
  return r;
}

// weight-form bilinear*line on 2 packed channels
__device__ __forceinline__ u32 blend2(u32 u00,u32 u01,u32 u10,u32 u11,u32 g0,u32 g1,
                                      float w00,float w01,float w10,float w11,
                                      float v0,float v1){
  f32x2 pf = bfx2(u00)*w00 + bfx2(u01)*w01 + bfx2(u10)*w10 + bfx2(u11)*w11;
  f32x2 lf = bfx2(g0)*v0 + bfx2(g1)*v1;
  f32x2 r  = pf*lf;
  return pack2bf_fast(r.x, r.y);
}

#define FSTRIDE 168   // feature LDS row stride (u16), 336B
#define HSTRIDE 264   // H LDS row stride (u16), 528B

// ---------------- fused gather + MLP, 256 threads / 16 points ----------------
// r4 evidence: occupancy pinned at 4 waves/SIMD by 48 VGPR + 56 AGPR = 104
// regs; launch_bounds couldn't shave it; VALU (55% = 160us of issue) is the
// top pipe and the kernel is latency-bound. Structural fix: M=16 per block ->
// each wave owns 1 m-tile x 4 n-tiles -> acc[4] = 16 AGPR (stage2 reuses
// acc[0..2]). Target ~64 total regs -> 8 waves/SIMD, 8 independent
// blocks/CU (LDS 8.4KB x 8 = 68KB), i.e. BOTH more latency hiding AND more
// phase decorrelation (the r3 lever, maxed out).
// Known cost: B-frags are re-read per m-tile -> weight L2 traffic doubles
// (~+84us of L2-busy) — overlappable if occupancy doubles. If occ jumps but
// dur doesn't, L2 weight bandwidth is the new bound -> stage B in LDS next.
// Gather: 16 threads/point; q=0..14 each own ONE 16B chunk (plane q/5,
// chunk q%5): 6 loads + 4 blends + 1 LDS store. q=15 does all PE (slots
// 120..159; 141..159 MUST be zero-written: uninit-LDS NaN x zero-weight
// poisons MFMA).
__global__ void __launch_bounds__(256, 6) k_main(
    const float* __restrict__ xyz, const u16* __restrict__ pt,
    const u16* __restrict__ lt, const u16* __restrict__ w1s,
    const u16* __restrict__ w2s, const float* __restrict__ b1,
    const float* __restrict__ b2, float* __restrict__ out)
{
  __shared__ __align__(16) u16 smem[16*HSTRIDE];   // 8,448 B; feat (stride 168) aliased by H (stride 264)
  const int tid = threadIdx.x;
  const int p = tid >> 4, q = tid & 15;            // 16 points, 16 roles
  const int gp = blockIdx.x*16 + p;
  const float u0 = xyz[gp*3], u1 = xyz[gp*3+1], u2 = xyz[gp*3+2];
  const float xn0 = 2.f*u0-1.f, xn1 = 2.f*u1-1.f, xn2 = 2.f*u2-1.f;

  if (q < 15){
    const int i = q/5, cc = q - i*5;   // plane 0..2, 16B-chunk 0..4
    // MAT_MODE=[(0,1),(0,2),(1,2)], VEC_MODE=[2,1,0]; x<-m0, y<-m1
    float gxv, gyv, gzv;
    if      (i==0){ gxv=xn0; gyv=xn1; gzv=xn2; }
    else if (i==1){ gxv=xn0; gyv=xn2; gzv=xn1; }
    else          { gxv=xn1; gyv=xn2; gzv=xn0; }
    float px=(gxv+1.0f)*0.5f*511.0f, py=(gyv+1.0f)*0.5f*511.0f, pz=(gzv+1.0f)*0.5f*511.0f;
    float fx=fminf(fmaxf(floorf(px),0.f),510.f);
    float fy=fminf(fmaxf(floorf(py),0.f),510.f);
    float fz=fminf(fmaxf(floorf(pz),0.f),510.f);
    int ix=(int)fx, iy=(int)fy, iz=(int)fz;
    float wx=px-fx, wy=py-fy, wz=pz-fz;
    const float cwx = 1.f-wx, cwy = 1.f-wy;
    const float w00 = cwx*cwy, w01 = wx*cwy, w10 = cwx*wy, w11 = wx*wy;
    const float v0 = 1.f-wz, v1 = wz;
    const u16* tb = pt + (size_t)((i<<18)+(iy<<9)+ix)*40 + cc*8;
    const u16* lb = lt + (size_t)((i<<9)+iz)*40 + cc*8;
    uint4 a00 = *reinterpret_cast<const uint4*>(tb);
    uint4 a01 = *reinterpret_cast<const uint4*>(tb + 40);
    uint4 a10 = *reinterpret_cast<const uint4*>(tb + 20480);
    uint4 a11 = *reinterpret_cast<const uint4*>(tb + 20520);
    uint4 e0  = *reinterpret_cast<const uint4*>(lb);
    uint4 e1  = *reinterpret_cast<const uint4*>(lb + 40);
    uint4 o;
    o.x = blend2(a00.x,a01.x,a10.x,a11.x,e0.x,e1.x, w00,w01,w10,w11,v0,v1);
    o.y = blend2(a00.y,a01.y,a10.y,a11.y,e0.y,e1.y, w00,w01,w10,w11,v0,v1);
    o.z = blend2(a00.z,a01.z,a10.z,a11.z,e0.z,e1.z, w00,w01,w10,w11,v0,v1);
    o.w = blend2(a00.w,a01.w,a10.w,a11.w,e0.w,e1.w, w00,w01,w10,w11,v0,v1);
    *reinterpret_cast<uint4*>(smem + p*FSTRIDE + i*40 + cc*8) = o;
  } else {
    // q==15: all PE. slots 120..140 = [x(3), sin/cos(x), sin/cos(2x), sin/cos(4x)],
    // slots 141..159 explicit zeros.
    float v[21];
    v[0]=xn0; v[1]=xn1; v[2]=xn2;
    v[3]=__sinf(xn0);      v[4]=__sinf(xn1);      v[5]=__sinf(xn2);
    v[6]=__cosf(xn0);      v[7]=__cosf(xn1);      v[8]=__cosf(xn2);
    v[9]=__sinf(2.f*xn0);  v[10]=__sinf(2.f*xn1); v[11]=__sinf(2.f*xn2);
    v[12]=__cosf(2.f*xn0); v[13]=__cosf(2.f*xn1); v[14]=__cosf(2.f*xn2);
    v[15]=__sinf(4.f*xn0); v[16]=__sinf(4.f*xn1); v[17]=__sinf(4.f*xn2);
    v[18]=__cosf(4.f*xn0); v[19]=__cosf(4.f*xn1); v[20]=__cosf(4.f*xn2);
    u16* dst = smem + p*FSTRIDE + 120;
#pragma unroll
    for (int c=0; c<10; c++)
      *reinterpret_cast<u32*>(dst + c*2) = pack2bf_fast(v[c*2], v[c*2+1]);
    *reinterpret_cast<u32*>(dst + 20) = pack2bf_fast(v[20], 0.f);
#pragma unroll
    for (int c=11; c<20; c++)
      *reinterpret_cast<u32*>(dst + c*2) = 0u;
  }
  __syncthreads();

  // ---- stage 1: H = softplus(100*(feat@W1+b1))/100, M=16 K=160 N=256 ----
  // 4 waves: wave w owns n-tiles w*4..w*4+3, the single m-tile. acc[4] = 16 AGPR.
  const int lane = tid & 63;
  const int w = tid >> 6;            // 0..3
  const int lm = lane & 15;
  const int quad = lane >> 4;
  const f32x4 zero = {0.f,0.f,0.f,0.f};
  f32x4 acc[4];                      // shared between stage1 and stage2 (stage2 uses [0..2])
#pragma unroll
  for (int nt=0; nt<4; nt++) acc[nt] = zero;

#pragma unroll
  for (int kt=0; kt<5; kt++){
    short8 a = *reinterpret_cast<const short8*>(smem + lm*FSTRIDE + kt*32 + quad*8);
    short8 b[4];
#pragma unroll
    for (int nt=0; nt<4; nt++)
      b[nt] = *reinterpret_cast<const short8*>(w1s + (size_t)(((w*4+nt)*5 + kt)*64 + lane)*8);
#pragma unroll
    for (int nt=0; nt<4; nt++)
      acc[nt] = __builtin_amdgcn_mfma_f32_16x16x32_bf16(a, b[nt], acc[nt], 0,0,0);
  }
  __syncthreads();   // all feat reads done before H overwrites the same LDS

#pragma unroll
  for (int nt=0; nt<4; nt++){
    int col = w*64 + nt*16 + lm;
    float bias = b1[col];
#pragma unroll
    for (int r=0; r<4; r++){
      float xv = acc[nt][r] + bias;
      float z = 100.f*xv;
      float y = (z > 15.f) ? xv : __logf(1.f + __expf(z))*0.01f;
      int row = quad*4 + r;
      smem[row*HSTRIDE + col] = f2bf_fast(y);
    }
  }
  // keep stage-2 accvgpr zero-inits below the epilogue's acc reads
  __builtin_amdgcn_sched_barrier(0);
  __syncthreads();

  // ---- stage 2: out = H@W2 + b2, M=16 K=256 N=144(->192 padded) ----
  // wave w owns n-tiles w*3..w*3+2. acc reuse: [0..2] of the same array.
#pragma unroll
  for (int nt=0; nt<3; nt++) acc[nt] = zero;

#pragma unroll
  for (int kt=0; kt<8; kt++){
    short8 a = *reinterpret_cast<const short8*>(smem + lm*HSTRIDE + kt*32 + quad*8);
    short8 b[3];
#pragma unroll
    for (int nt=0; nt<3; nt++){
      int ntg = w*3 + nt;
      b[nt] = *reinterpret_cast<const short8*>(w2s + (size_t)((ntg*8 + kt)*64 + lane)*8);
    }
#pragma unroll
    for (int nt=0; nt<3; nt++)
      acc[nt] = __builtin_amdgcn_mfma_f32_16x16x32_bf16(a, b[nt], acc[nt], 0,0,0);
  }

  // plain cached stores (r1: nontemporal doubled WRITE_SIZE)
#pragma unroll
  for (int nt=0; nt<3; nt++){
    int j = (w*3 + nt)*16 + lm;
    if (j < 129){
      float bias = b2[j];
#pragma unroll
      for (int r=0; r<4; r++){
        int row = quad*4 + r;
        out[(size_t)(blockIdx.x*16 + row)*129 + j] = acc[nt][r] + bias;
      }
    }
  }
}

extern "C" void kernel_launch(void* const* d_in, const int* in_sizes, int n_in,
                              void* d_out, int out_size, void* d_ws, size_t ws_size,
                              hipStream_t stream) {
  const float* xyz    = (const float*)d_in[0];
  const float* planes = (const float*)d_in[1];
  const float* lines  = (const float*)d_in[2];
  const float* W1     = (const float*)d_in[3];
  const float* b1     = (const float*)d_in[4];
  const float* W2     = (const float*)d_in[5];
  const float* b2     = (const float*)d_in[6];
  if (ws_size < (size_t)WS_NEEDED) return;   // workspace too small: fail loudly

  u16* pt  = (u16*)((char*)d_ws);
  u16* lt  = (u16*)((char*)d_ws + OFF_LINES_T);
  u16* w1s = (u16*)((char*)d_ws + OFF_W1S);
  u16* w2s = (u16*)((char*)d_ws + OFF_W2S);

  k_pre<<<NB_TP+NB_TL+NB_W1+NB_W2, 256, 0, stream>>>(planes, lines, W1, W2, pt, lt, w1s, w2s);
  k_main<<<32768, 256, 0, stream>>>(xyz, pt, lt, w1s, w2s, b1, b2, (float*)d_out);
}

// Round 6
// 597.883 us; speedup vs baseline: 1.0415x; 1.0415x over previous
//
#include <hip/hip_runtime.h>
#include <math.h>

typedef unsigned short u16;
typedef unsigned int u32;
typedef __attribute__((ext_vector_type(2))) u32 u32x2;
typedef __attribute__((ext_vector_type(8))) short short8;
typedef __attribute__((ext_vector_type(4))) float f32x4;
typedef __attribute__((ext_vector_type(2))) float f32x2;

// ---------------- workspace layout (bytes) ----------------
// planes_t: 3*512*512 texels * 40 bf16 ch (c>=36 zero)   = 62,914,560
// lines_t : 3*512 texels * 40 bf16                        =    122,880
// w1s     : 16 nt * 5 kt * 64 lanes * 8 bf16              =     81,920
// w2s     : 12 nt * 8 kt * 64 lanes * 8 bf16              =     98,304
#define OFF_LINES_T 62914560u
#define OFF_W1S     63037440u
#define OFF_W2S     63119360u
#define WS_NEEDED   63217664u

__device__ __forceinline__ float bf_lo(u32 u){ union{u32 i;float f;} v; v.i = u << 16; return v.f; }
__device__ __forceinline__ float bf_hi(u32 u){ union{u32 i;float f;} v; v.i = u & 0xffff0000u; return v.f; }
// RTNE pack (precompute kernels only — cost irrelevant there)
__device__ __forceinline__ u16 f2bf(float f){ union{float f;u32 i;} v; v.f=f; u32 i=v.i; return (u16)((i + 0x7fffu + ((i>>16)&1u)) >> 16); }
__device__ __forceinline__ u32 pack2bf(float lo, float hi){ return (u32)f2bf(lo) | ((u32)f2bf(hi)<<16); }
// fast round-half-up pack: 2 adds + v_perm (vs ~9 inst RTNE); error <= 0.5 ulp
__device__ __forceinline__ u32 pack2bf_fast(float lo, float hi){
  return __builtin_amdgcn_perm(__float_as_uint(hi) + 0x8000u,
                               __float_as_uint(lo) + 0x8000u, 0x07060302u);
}
__device__ __forceinline__ u16 f2bf_fast(float f){ return (u16)((__float_as_uint(f) + 0x8000u) >> 16); }

// LDS k'-layout (160 slots): [0..35]=mode0, [36..39]=0, [40..75]=mode1, [76..79]=0,
// [80..115]=mode2, [116..119]=0, [120..140]=PE(21), [141..159]=0.
__device__ __forceinline__ int map_k1(int kp){
  if (kp < 120){ int g = kp/40, r = kp - g*40; return (r<36) ? g*36 + r : -1; }
  if (kp < 141) return kp - 12;   // 108 + (kp-120)
  return -1;
}

// ---------------- fused precompute: all transposes in ONE launch ----------------
// r4 evidence: k_pre is small (never in top-5; two radically different store
// patterns time identically); residual ~300us is harness-fixed. Keeping the
// chunk-per-thread version (coalesced stores, near-coalesced reads).
#define NB_TP 15360
#define NB_TL 30
#define NB_W1 20
#define NB_W2 24
__global__ void k_pre(const float* __restrict__ planes, const float* __restrict__ lines,
                      const float* __restrict__ W1, const float* __restrict__ W2,
                      u16* __restrict__ pt, u16* __restrict__ lt,
                      u16* __restrict__ w1s, u16* __restrict__ w2s){
  const int b = blockIdx.x;
  const int tid = threadIdx.x;
  if (b < NB_TP){
    int m = b*256 + tid;                // chunk id 0..3,932,159
    int tt = m/5, cc = m - tt*5;        // texel 0..786431, chunk-in-texel 0..4
    int i = tt >> 18;
    int yx = tt & 262143;
    const float* src = planes + (size_t)i*9437184 + yx;   // i*36*262144 + y*512 + x
    int cbase = cc*8;
    float v[8];
#pragma unroll
    for (int e=0;e<8;e++) v[e] = 0.f;
    if (cc < 4){
#pragma unroll
      for (int e=0;e<8;e++) v[e] = src[(size_t)(cbase+e)*262144];
    } else {
#pragma unroll
      for (int e=0;e<4;e++) v[e] = src[(size_t)(32+e)*262144];
    }
    uint4 o; o.x=pack2bf(v[0],v[1]); o.y=pack2bf(v[2],v[3]); o.z=pack2bf(v[4],v[5]); o.w=pack2bf(v[6],v[7]);
    *reinterpret_cast<uint4*>(pt + (size_t)m*8) = o;      // byte m*16: lane-consecutive
  } else if (b < NB_TP+NB_TL){
    int m = (b-NB_TP)*256 + tid;        // chunk id 0..7679
    int tt = m/5, cc = m - tt*5;        // texel 0..1535
    int i = tt >> 9, g = tt & 511;
    const float* src = lines + (size_t)i*18432 + g;       // i*36*512 + g
    int cbase = cc*8;
    float v[8];
#pragma unroll
    for (int e=0;e<8;e++) v[e] = 0.f;
    if (cc < 4){
#pragma unroll
      for (int e=0;e<8;e++) v[e] = src[(size_t)(cbase+e)*512];
    } else {
#pragma unroll
      for (int e=0;e<4;e++) v[e] = src[(size_t)(32+e)*512];
    }
    uint4 o; o.x=pack2bf(v[0],v[1]); o.y=pack2bf(v[2],v[3]); o.z=pack2bf(v[4],v[5]); o.w=pack2bf(v[6],v[7]);
    *reinterpret_cast<uint4*>(lt + (size_t)m*8) = o;
  } else if (b < NB_TP+NB_TL+NB_W1){
    int t = (b-(NB_TP+NB_TL))*256 + tid;         // 0..5119 = 80 frags * 64 lanes
    int lane = t & 63;
    int fid = t >> 6;                            // nt*5 + kt
    int nt = fid/5, kt = fid - nt*5;
    int n = nt*16 + (lane & 15);
    int kb = kt*32 + (lane >> 4)*8;
    float v[8];
#pragma unroll
    for (int j=0;j<8;j++){ int k = map_k1(kb+j); v[j] = (k>=0) ? W1[k*256+n] : 0.f; }
    uint4 o; o.x=pack2bf(v[0],v[1]); o.y=pack2bf(v[2],v[3]); o.z=pack2bf(v[4],v[5]); o.w=pack2bf(v[6],v[7]);
    *reinterpret_cast<uint4*>(w1s + (size_t)t*8) = o;
  } else {
    int t = (b-(NB_TP+NB_TL+NB_W1))*256 + tid;   // 0..6143 = 96 frags * 64 lanes
    int lane = t & 63;
    int fid = t >> 6;                            // nt*8 + kt
    int kb = (fid & 7)*32 + (lane >> 4)*8;
    int n = (fid >> 3)*16 + (lane & 15);
    float v[8];
#pragma unroll
    for (int j=0;j<8;j++){ int k = kb+j; v[j] = (n<129) ? W2[k*129+n] : 0.f; }
    uint4 o; o.x=pack2bf(v[0],v[1]); o.y=pack2bf(v[2],v[3]); o.z=pack2bf(v[4],v[5]); o.w=pack2bf(v[6],v[7]);
    *reinterpret_cast<uint4*>(w2s + (size_t)t*8) = o;
  }
}

// unpack 2 packed bf16 -> float2 (2 VALU)
__device__ __forceinline__ f32x2 bfx2(u32 u){
  f32x2 r;
  r.x = __uint_as_float(u << 16);
  r.y = __uint_as_float(u & 0xffff0000u);
  return r;
}

// weight-form bilinear*line on 2 packed channels
__device__ __forceinline__ u32 blend2(u32 u00,u32 u01,u32 u10,u32 u11,u32 g0,u32 g1,
                                      float w00,float w01,float w10,float w11,
                                      float v0,float v1){
  f32x2 pf = bfx2(u00)*w00 + bfx2(u01)*w01 + bfx2(u10)*w10 + bfx2(u11)*w11;
  f32x2 lf = bfx2(g0)*v0 + bfx2(g1)*v1;
  f32x2 r  = pf*lf;
  return pack2bf_fast(r.x, r.y);
}

#define FSTRIDE 168   // feature LDS row stride (u16), 336B
#define HSTRIDE 264   // H LDS row stride (u16), 528B

// ---------------- fused gather + MLP, 256 threads / 32 points ----------------
// r5 evidence: M=16 regressed (328us @ 64% occ): weight L2 traffic doubled AND
// per-point setup VALU doubled (total VALU-cycles 160->184us). VALU inst count
// is the binding metric. Back to M=32 (r4 = 290us) + ONE change:
// WAVE-UNIFORM ROLE SPECIALIZATION. r4's q=tid&7 roles put gather lanes AND
// PE lanes in every wave -> each wave serially executed BOTH branch bodies
// (~320-inst gather + ~130-inst PE) under exec masks. Now:
//   waves 0-2: gather plane i=w for all 32 points (lane>>1 = point,
//              lane&1 = part, asym 24/16 chunk split) — plane select is
//              wave-uniform, zero divergence.
//   wave 3   : PE, one lane per point (lanes 0-31, single body; lanes 32-63
//              idle during phase 1 — cheaper than a second serialized body).
// Slots 140..159 MUST be written (uninit-LDS NaN x zero-weight poisons MFMA).
__global__ void __launch_bounds__(256, 4) k_main(
    const float* __restrict__ xyz, const u16* __restrict__ pt,
    const u16* __restrict__ lt, const u16* __restrict__ w1s,
    const u16* __restrict__ w2s, const float* __restrict__ b1,
    const float* __restrict__ b2, float* __restrict__ out)
{
  __shared__ __align__(16) u16 smem[32*HSTRIDE];   // 16,896 B; feat (stride 168) aliased by H (stride 264)
  const int tid = threadIdx.x;
  const int lane = tid & 63;
  const int w = tid >> 6;            // wave id 0..3
  // phase-1 point served by this thread
  const int myp = (w < 3) ? (lane >> 1) : (lane & 31);
  const int gp = blockIdx.x*32 + myp;
  const float u0 = xyz[gp*3], u1 = xyz[gp*3+1], u2 = xyz[gp*3+2];
  const float xn0 = 2.f*u0-1.f, xn1 = 2.f*u1-1.f, xn2 = 2.f*u2-1.f;

  if (w < 3){
    const int i = w;                 // plane id — WAVE-UNIFORM
    const int part = lane & 1;
    // MAT_MODE=[(0,1),(0,2),(1,2)], VEC_MODE=[2,1,0]; x<-m0, y<-m1
    float gxv, gyv, gzv;
    if      (i==0){ gxv=xn0; gyv=xn1; gzv=xn2; }
    else if (i==1){ gxv=xn0; gyv=xn2; gzv=xn1; }
    else          { gxv=xn1; gyv=xn2; gzv=xn0; }
    float px=(gxv+1.0f)*0.5f*511.0f, py=(gyv+1.0f)*0.5f*511.0f, pz=(gzv+1.0f)*0.5f*511.0f;
    float fx=fminf(fmaxf(floorf(px),0.f),510.f);
    float fy=fminf(fmaxf(floorf(py),0.f),510.f);
    float fz=fminf(fmaxf(floorf(pz),0.f),510.f);
    int ix=(int)fx, iy=(int)fy, iz=(int)fz;
    float wx=px-fx, wy=py-fy, wz=pz-fz;
    const float cwx = 1.f-wx, cwy = 1.f-wy;
    const float w00 = cwx*cwy, w01 = wx*cwy, w10 = cwx*wy, w11 = wx*wy;
    const float v0 = 1.f-wz, v1 = wz;
    const int nch = part ? 2 : 3;              // 16B chunks this thread owns (asym 24/16 split)
    const u16* tb = pt + (size_t)((i<<18)+(iy<<9)+ix)*40 + part*24;
    const u16* lb = lt + (size_t)((i<<9)+iz)*40 + part*24;
    u16* dst = smem + myp*FSTRIDE + i*40 + part*24;
#pragma unroll
    for (int ch=0; ch<3; ch++){
      if (ch < nch){
        uint4 a00 = *reinterpret_cast<const uint4*>(tb + ch*8);
        uint4 a01 = *reinterpret_cast<const uint4*>(tb + 40 + ch*8);
        uint4 a10 = *reinterpret_cast<const uint4*>(tb + 20480 + ch*8);
        uint4 a11 = *reinterpret_cast<const uint4*>(tb + 20520 + ch*8);
        uint4 e0  = *reinterpret_cast<const uint4*>(lb + ch*8);
        uint4 e1  = *reinterpret_cast<const uint4*>(lb + 40 + ch*8);
        uint4 o;
        o.x = blend2(a00.x,a01.x,a10.x,a11.x,e0.x,e1.x, w00,w01,w10,w11,v0,v1);
        o.y = blend2(a00.y,a01.y,a10.y,a11.y,e0.y,e1.y, w00,w01,w10,w11,v0,v1);
        o.z = blend2(a00.z,a01.z,a10.z,a11.z,e0.z,e1.z, w00,w01,w10,w11,v0,v1);
        o.w = blend2(a00.w,a01.w,a10.w,a11.w,e0.w,e1.w, w00,w01,w10,w11,v0,v1);
        *reinterpret_cast<uint4*>(dst + ch*8) = o;
      }
    }
  } else if (lane < 32){
    // wave 3: full PE for point myp. slots 120..140 = [x(3), sin/cos(x),
    // sin/cos(2x), sin/cos(4x)], slots 141..159 explicit zeros.
    float v[21];
    v[0]=xn0; v[1]=xn1; v[2]=xn2;
    v[3]=__sinf(xn0);      v[4]=__sinf(xn1);      v[5]=__sinf(xn2);
    v[6]=__cosf(xn0);      v[7]=__cosf(xn1);      v[8]=__cosf(xn2);
    v[9]=__sinf(2.f*xn0);  v[10]=__sinf(2.f*xn1); v[11]=__sinf(2.f*xn2);
    v[12]=__cosf(2.f*xn0); v[13]=__cosf(2.f*xn1); v[14]=__cosf(2.f*xn2);
    v[15]=__sinf(4.f*xn0); v[16]=__sinf(4.f*xn1); v[17]=__sinf(4.f*xn2);
    v[18]=__cosf(4.f*xn0); v[19]=__cosf(4.f*xn1); v[20]=__cosf(4.f*xn2);
    u16* dst = smem + myp*FSTRIDE + 120;
#pragma unroll
    for (int c=0; c<10; c++)
      *reinterpret_cast<u32*>(dst + c*2) = pack2bf_fast(v[c*2], v[c*2+1]);
    *reinterpret_cast<u32*>(dst + 20) = pack2bf_fast(v[20], 0.f);
#pragma unroll
    for (int c=11; c<20; c++)
      *reinterpret_cast<u32*>(dst + c*2) = 0u;
  }
  __syncthreads();

  // ---- stage 1: H = softplus(100*(feat@W1+b1))/100, M=32 K=160 N=256 ----
  // 4 waves: wave w owns n-tiles w*4..w*4+3, both m-tiles. acc[2][4] = 32 AGPR.
  const int lm = lane & 15;
  const int quad = lane >> 4;
  const f32x4 zero = {0.f,0.f,0.f,0.f};
  f32x4 acc[2][4];                   // shared between stage1 and stage2
#pragma unroll
  for (int mt=0; mt<2; mt++)
#pragma unroll
    for (int nt=0; nt<4; nt++) acc[mt][nt] = zero;

#pragma unroll
  for (int kt=0; kt<5; kt++){
    short8 a[2];
#pragma unroll
    for (int mt=0; mt<2; mt++)
      a[mt] = *reinterpret_cast<const short8*>(smem + (mt*16 + lm)*FSTRIDE + kt*32 + quad*8);
    short8 b[4];
#pragma unroll
    for (int nt=0; nt<4; nt++)
      b[nt] = *reinterpret_cast<const short8*>(w1s + (size_t)(((w*4+nt)*5 + kt)*64 + lane)*8);
#pragma unroll
    for (int mt=0; mt<2; mt++)
#pragma unroll
      for (int nt=0; nt<4; nt++)
        acc[mt][nt] = __builtin_amdgcn_mfma_f32_16x16x32_bf16(a[mt], b[nt], acc[mt][nt], 0,0,0);
  }
  __syncthreads();   // all feat reads done before H overwrites the same LDS

#pragma unroll
  for (int nt=0; nt<4; nt++){
    int col = w*64 + nt*16 + lm;
    float bias = b1[col];
#pragma unroll
    for (int mt=0; mt<2; mt++){
#pragma unroll
      for (int r=0; r<4; r++){
        float xv = acc[mt][nt][r] + bias;
        float z = 100.f*xv;
        float y = (z > 15.f) ? xv : __logf(1.f + __expf(z))*0.01f;
        int row = mt*16 + quad*4 + r;
        smem[row*HSTRIDE + col] = f2bf_fast(y);
      }
    }
  }
  // keep stage-2 accvgpr zero-inits below the epilogue's acc reads
  __builtin_amdgcn_sched_barrier(0);
  __syncthreads();

  // ---- stage 2: out = H@W2 + b2, M=32 K=256 N=144(->192 padded) ----
  // wave w owns n-tiles w*3..w*3+2. acc reuse: [2][3] of the same array.
#pragma unroll
  for (int mt=0; mt<2; mt++)
#pragma unroll
    for (int nt=0; nt<3; nt++) acc[mt][nt] = zero;

#pragma unroll
  for (int kt=0; kt<8; kt++){
    short8 a[2];
#pragma unroll
    for (int mt=0; mt<2; mt++)
      a[mt] = *reinterpret_cast<const short8*>(smem + (mt*16 + lm)*HSTRIDE + kt*32 + quad*8);
    short8 b[3];
#pragma unroll
    for (int nt=0; nt<3; nt++){
      int ntg = w*3 + nt;
      b[nt] = *reinterpret_cast<const short8*>(w2s + (size_t)((ntg*8 + kt)*64 + lane)*8);
    }
#pragma unroll
    for (int mt=0; mt<2; mt++)
#pragma unroll
      for (int nt=0; nt<3; nt++)
        acc[mt][nt] = __builtin_amdgcn_mfma_f32_16x16x32_bf16(a[mt], b[nt], acc[mt][nt], 0,0,0);
  }

  // plain cached stores (r1: nontemporal doubled WRITE_SIZE)
#pragma unroll
  for (int nt=0; nt<3; nt++){
    int j = (w*3 + nt)*16 + lm;
    if (j < 129){
      float bias = b2[j];
#pragma unroll
      for (int mt=0; mt<2; mt++){
#pragma unroll
        for (int r=0; r<4; r++){
          int row = mt*16 + quad*4 + r;
          out[(size_t)(blockIdx.x*32 + row)*129 + j] = acc[mt][nt][r] + bias;
        }
      }
    }
  }
}

extern "C" void kernel_launch(void* const* d_in, const int* in_sizes, int n_in,
                              void* d_out, int out_size, void* d_ws, size_t ws_size,
                              hipStream_t stream) {
  const float* xyz    = (const float*)d_in[0];
  const float* planes = (const float*)d_in[1];
  const float* lines  = (const float*)d_in[2];
  const float* W1     = (const float*)d_in[3];
  const float* b1     = (const float*)d_in[4];
  const float* W2     = (const float*)d_in[5];
  const float* b2     = (const float*)d_in[6];
  if (ws_size < (size_t)WS_NEEDED) return;   // workspace too small: fail loudly

  u16* pt  = (u16*)((char*)d_ws);
  u16* lt  = (u16*)((char*)d_ws + OFF_LINES_T);
  u16* w1s = (u16*)((char*)d_ws + OFF_W1S);
  u16* w2s = (u16*)((char*)d_ws + OFF_W2S);

  k_pre<<<NB_TP+NB_TL+NB_W1+NB_W2, 256, 0, stream>>>(planes, lines, W1, W2, pt, lt, w1s, w2s);
  k_main<<<16384, 256, 0, stream>>>(xyz, pt, lt, w1s, w2s, b1, b2, (float*)d_out);
}